// Round 4
// baseline (245.734 us; speedup 1.0000x reference)
//
#include <hip/hip_runtime.h>

// Coords are all {0,1}; STRIDES is a mixed-radix positional encoding, so each
// row maps bijectively to a 16-bit pattern. Whole op = 65536-bin float
// histogram + gather.
//
// R0-R2 evidence: global fp32 atomicAdd executes at the memory-side coherence
// point regardless of scope (WRITE_SIZE == n_atomics*32B, ~19G ops/s cap).
// R3: eliminate global atomics entirely.
//   K1: coords -> u16 patterns (the only pass that touches the 266MB input)
//   K2: 4 key-space partitions x 32 input slices, 64KB-LDS histogram per
//       block (LDS fp atomics are on-CU and cheap), non-atomic flush
//   K2b: reduce 32 slice-copies -> final 256KB hist
//   K3: gather out[i] = hist[pat_q[i]]

#define REL_W 16
#define NBINS 65536
#define NPART 4
#define BPP 16384      // bins per partition (64 KB as floats)
#define NSLICES 32

__device__ __forceinline__ unsigned pattern_of(const int* __restrict__ row) {
    const int4* p = reinterpret_cast<const int4*>(row);
    unsigned pat = 0;
#pragma unroll
    for (int k = 0; k < 4; ++k) {
        int4 v = p[k];
        pat |= (unsigned)(v.x & 1) << (k * 4 + 0);
        pat |= (unsigned)(v.y & 1) << (k * 4 + 1);
        pat |= (unsigned)(v.z & 1) << (k * 4 + 2);
        pat |= (unsigned)(v.w & 1) << (k * 4 + 3);
    }
    return pat;
}

__global__ void extract_patterns(const int* __restrict__ a, unsigned short* __restrict__ pa, int na,
                                 const int* __restrict__ b, unsigned short* __restrict__ pb, int nb) {
    int total = na + nb;
    int stride = gridDim.x * blockDim.x;
    for (int i = blockIdx.x * blockDim.x + threadIdx.x; i < total; i += stride) {
        if (i < na)
            pa[i] = (unsigned short)pattern_of(a + (size_t)i * REL_W);
        else
            pb[i - na] = (unsigned short)pattern_of(b + (size_t)(i - na) * REL_W);
    }
}

__global__ __launch_bounds__(256) void build_parts(const unsigned short* __restrict__ pats,
                                                   const float* __restrict__ vals,
                                                   float* __restrict__ part_hists, int n) {
    extern __shared__ float lh[];
    unsigned part  = blockIdx.x / NSLICES;
    unsigned slice = blockIdx.x % NSLICES;
    for (int b = threadIdx.x; b < BPP; b += blockDim.x) lh[b] = 0.0f;
    __syncthreads();
    int per = (n + NSLICES - 1) / NSLICES;
    int lo = (int)slice * per;
    int hi = min(n, lo + per);
    for (int i = lo + (int)threadIdx.x; i < hi; i += (int)blockDim.x) {
        unsigned pat = pats[i];
        if ((pat >> 14) == part)
            atomicAdd(&lh[pat & (BPP - 1)], vals[i]);   // ds_add_f32, on-CU
    }
    __syncthreads();
    float* dst = part_hists + (size_t)blockIdx.x * BPP;
    for (int b = threadIdx.x; b < BPP; b += blockDim.x) dst[b] = lh[b];
}

__global__ void reduce_parts(const float* __restrict__ part_hists, float* __restrict__ final_h) {
    int g = blockIdx.x * blockDim.x + threadIdx.x;   // bin 0..65535
    unsigned part = (unsigned)g >> 14;
    unsigned b = (unsigned)g & (BPP - 1);
    const float* src = part_hists + (size_t)part * NSLICES * BPP + b;
    float s = 0.0f;
#pragma unroll
    for (int sl = 0; sl < NSLICES; ++sl) s += src[(size_t)sl * BPP];
    final_h[g] = s;
}

__global__ void gather_pat(const unsigned short* __restrict__ pq, const float* __restrict__ h,
                           float* __restrict__ out, int n) {
    int stride = gridDim.x * blockDim.x;
    for (int i = blockIdx.x * blockDim.x + threadIdx.x; i < n; i += stride)
        out[i] = h[pq[i]];
}

// ---- fallback (R0 path) if workspace too small ----
__global__ void build_hist_dev(const int* __restrict__ coords, const float* __restrict__ vals,
                               float* __restrict__ hist, int n) {
    int i = blockIdx.x * blockDim.x + threadIdx.x;
    if (i >= n) return;
    atomicAdd(&hist[pattern_of(coords + (size_t)i * REL_W)], vals[i]);
}
__global__ void gather_coord(const int* __restrict__ queries, const float* __restrict__ hist,
                             float* __restrict__ out, int n) {
    int i = blockIdx.x * blockDim.x + threadIdx.x;
    if (i >= n) return;
    out[i] = hist[pattern_of(queries + (size_t)i * REL_W)];
}

static inline size_t align_up(size_t x, size_t a) { return (x + a - 1) & ~(a - 1); }

extern "C" void kernel_launch(void* const* d_in, const int* in_sizes, int n_in,
                              void* d_out, int out_size, void* d_ws, size_t ws_size,
                              hipStream_t stream) {
    const int*   stored  = (const int*)d_in[0];   // [N_store, 16] int32
    const int*   queries = (const int*)d_in[1];   // [N_query, 16] int32
    const float* vals    = (const float*)d_in[2]; // [N_store] f32
    float*       out     = (float*)d_out;         // [N_query] f32

    int n_store = in_sizes[0] / REL_W;
    int n_query = in_sizes[1] / REL_W;

    const int BLK = 256;

    // workspace layout
    size_t off_pat_s = 0;
    size_t off_pat_q = align_up(off_pat_s + (size_t)n_store * 2, 256);
    size_t off_hists = align_up(off_pat_q + (size_t)n_query * 2, 256);
    size_t off_final = off_hists + (size_t)NPART * NSLICES * BPP * sizeof(float);
    size_t need      = off_final + (size_t)NBINS * sizeof(float);

    if (ws_size >= need) {
        unsigned short* pat_s = (unsigned short*)((char*)d_ws + off_pat_s);
        unsigned short* pat_q = (unsigned short*)((char*)d_ws + off_pat_q);
        float* part_hists     = (float*)((char*)d_ws + off_hists);
        float* final_h        = (float*)((char*)d_ws + off_final);

        extract_patterns<<<2048, BLK, 0, stream>>>(stored, pat_s, n_store, queries, pat_q, n_query);
        build_parts<<<NPART * NSLICES, BLK, BPP * sizeof(float), stream>>>(pat_s, vals, part_hists, n_store);
        reduce_parts<<<NBINS / BLK, BLK, 0, stream>>>(part_hists, final_h);
        gather_pat<<<2048, BLK, 0, stream>>>(pat_q, final_h, out, n_query);
    } else {
        float* hist = (float*)d_ws;
        hipMemsetAsync(d_ws, 0, NBINS * sizeof(float), stream);
        build_hist_dev<<<(n_store + BLK - 1) / BLK, BLK, 0, stream>>>(stored, vals, hist, n_store);
        gather_coord<<<(n_query + BLK - 1) / BLK, BLK, 0, stream>>>(queries, hist, out, n_query);
    }
}

// Round 5
// 78.732 us; speedup vs baseline: 3.1211x; 3.1211x over previous
//
#include <hip/hip_runtime.h>

// Coords are all {0,1}; STRIDES is a mixed-radix positional encoding, so each
// row maps bijectively to a 16-bit pattern. Whole op = 65536-bin float
// histogram + gather.
//
// R0-R2: global fp32 atomicAdd executes at the memory-side coherence point
// regardless of scope (~19G ops/s cap) -> no global atomics anywhere.
// R3: LDS-partitioned build was right but latency-starved (5% occupancy,
// scalar unpipelined loop). R4: 32KB LDS hist (8 parts x 8192 bins),
// 1024-thread blocks (2/CU = 32 waves/CU), ushort8/float4 vectorized loop.

#define REL_W 16
#define NBINS 65536
#define NPART 8
#define BPP 8192        // bins per partition (32 KB as floats)
#define NSLICES 64
#define BUILD_BLK 1024

typedef unsigned short ushort8 __attribute__((ext_vector_type(8)));

__device__ __forceinline__ unsigned pattern_of(const int* __restrict__ row) {
    const int4* p = reinterpret_cast<const int4*>(row);
    unsigned pat = 0;
#pragma unroll
    for (int k = 0; k < 4; ++k) {
        int4 v = p[k];
        pat |= (unsigned)(v.x & 1) << (k * 4 + 0);
        pat |= (unsigned)(v.y & 1) << (k * 4 + 1);
        pat |= (unsigned)(v.z & 1) << (k * 4 + 2);
        pat |= (unsigned)(v.w & 1) << (k * 4 + 3);
    }
    return pat;
}

__global__ void extract_patterns(const int* __restrict__ a, unsigned short* __restrict__ pa, int na,
                                 const int* __restrict__ b, unsigned short* __restrict__ pb, int nb) {
    int total = na + nb;
    int stride = gridDim.x * blockDim.x;
    for (int i = blockIdx.x * blockDim.x + threadIdx.x; i < total; i += stride) {
        if (i < na)
            pa[i] = (unsigned short)pattern_of(a + (size_t)i * REL_W);
        else
            pb[i - na] = (unsigned short)pattern_of(b + (size_t)(i - na) * REL_W);
    }
}

__global__ __launch_bounds__(BUILD_BLK) void build_parts(const unsigned short* __restrict__ pats,
                                                         const float* __restrict__ vals,
                                                         float* __restrict__ part_hists, int n) {
    __shared__ float lh[BPP];
    unsigned part  = blockIdx.x / NSLICES;
    unsigned slice = blockIdx.x % NSLICES;
    for (int b = threadIdx.x; b < BPP; b += BUILD_BLK) lh[b] = 0.0f;
    __syncthreads();

    // slice bounds, lo aligned to 8 items so ushort8/float4 loads are 16B-aligned
    int per = ((n + NSLICES - 1) / NSLICES + 7) & ~7;
    int lo = (int)slice * per;
    int hi = min(n, lo + per);

    if (lo < hi) {
        int m = hi - lo;
        int nvec = m >> 3;
        const ushort8* pv = reinterpret_cast<const ushort8*>(pats + lo);
        const float4*  vv = reinterpret_cast<const float4*>(vals + lo);
        for (int v = threadIdx.x; v < nvec; v += BUILD_BLK) {
            ushort8 p8 = pv[v];
            float4 v0 = vv[2 * v];
            float4 v1 = vv[2 * v + 1];
            float vsc[8] = {v0.x, v0.y, v0.z, v0.w, v1.x, v1.y, v1.z, v1.w};
#pragma unroll
            for (int k = 0; k < 8; ++k) {
                unsigned pat = p8[k];
                if ((pat >> 13) == part)
                    atomicAdd(&lh[pat & (BPP - 1)], vsc[k]);   // ds_add_f32, on-CU
            }
        }
        // scalar tail
        for (int i = lo + (nvec << 3) + (int)threadIdx.x; i < hi; i += BUILD_BLK) {
            unsigned pat = pats[i];
            if ((pat >> 13) == part)
                atomicAdd(&lh[pat & (BPP - 1)], vals[i]);
        }
    }
    __syncthreads();
    float* dst = part_hists + (size_t)blockIdx.x * BPP;
    for (int b = threadIdx.x; b < BPP; b += BUILD_BLK) dst[b] = lh[b];
}

__global__ void reduce_parts(const float* __restrict__ part_hists, float* __restrict__ final_h) {
    int g = blockIdx.x * blockDim.x + threadIdx.x;   // bin 0..65535
    unsigned part = (unsigned)g >> 13;
    unsigned b = (unsigned)g & (BPP - 1);
    const float* src = part_hists + ((size_t)part * NSLICES) * BPP + b;
    float s = 0.0f;
#pragma unroll 8
    for (int sl = 0; sl < NSLICES; ++sl) s += src[(size_t)sl * BPP];
    final_h[g] = s;
}

__global__ void gather_pat(const unsigned short* __restrict__ pq, const float* __restrict__ h,
                           float* __restrict__ out, int n) {
    int stride = gridDim.x * blockDim.x;
    for (int i = blockIdx.x * blockDim.x + threadIdx.x; i < n; i += stride)
        out[i] = h[pq[i]];
}

// ---- fallback (R0 path) if workspace too small ----
__global__ void build_hist_dev(const int* __restrict__ coords, const float* __restrict__ vals,
                               float* __restrict__ hist, int n) {
    int i = blockIdx.x * blockDim.x + threadIdx.x;
    if (i >= n) return;
    atomicAdd(&hist[pattern_of(coords + (size_t)i * REL_W)], vals[i]);
}
__global__ void gather_coord(const int* __restrict__ queries, const float* __restrict__ hist,
                             float* __restrict__ out, int n) {
    int i = blockIdx.x * blockDim.x + threadIdx.x;
    if (i >= n) return;
    out[i] = hist[pattern_of(queries + (size_t)i * REL_W)];
}

static inline size_t align_up(size_t x, size_t a) { return (x + a - 1) & ~(a - 1); }

extern "C" void kernel_launch(void* const* d_in, const int* in_sizes, int n_in,
                              void* d_out, int out_size, void* d_ws, size_t ws_size,
                              hipStream_t stream) {
    const int*   stored  = (const int*)d_in[0];   // [N_store, 16] int32
    const int*   queries = (const int*)d_in[1];   // [N_query, 16] int32
    const float* vals    = (const float*)d_in[2]; // [N_store] f32
    float*       out     = (float*)d_out;         // [N_query] f32

    int n_store = in_sizes[0] / REL_W;
    int n_query = in_sizes[1] / REL_W;

    const int BLK = 256;

    // workspace layout
    size_t off_pat_s = 0;
    size_t off_pat_q = align_up(off_pat_s + (size_t)n_store * 2, 256);
    size_t off_hists = align_up(off_pat_q + (size_t)n_query * 2, 256);
    size_t off_final = off_hists + (size_t)NPART * NSLICES * BPP * sizeof(float);
    size_t need      = off_final + (size_t)NBINS * sizeof(float);

    if (ws_size >= need) {
        unsigned short* pat_s = (unsigned short*)((char*)d_ws + off_pat_s);
        unsigned short* pat_q = (unsigned short*)((char*)d_ws + off_pat_q);
        float* part_hists     = (float*)((char*)d_ws + off_hists);
        float* final_h        = (float*)((char*)d_ws + off_final);

        extract_patterns<<<2048, BLK, 0, stream>>>(stored, pat_s, n_store, queries, pat_q, n_query);
        build_parts<<<NPART * NSLICES, BUILD_BLK, 0, stream>>>(pat_s, vals, part_hists, n_store);
        reduce_parts<<<NBINS / BLK, BLK, 0, stream>>>(part_hists, final_h);
        gather_pat<<<2048, BLK, 0, stream>>>(pat_q, final_h, out, n_query);
    } else {
        float* hist = (float*)d_ws;
        hipMemsetAsync(d_ws, 0, NBINS * sizeof(float), stream);
        build_hist_dev<<<(n_store + BLK - 1) / BLK, BLK, 0, stream>>>(stored, vals, hist, n_store);
        gather_coord<<<(n_query + BLK - 1) / BLK, BLK, 0, stream>>>(queries, hist, out, n_query);
    }
}